// Round 1
// baseline (5428.666 us; speedup 1.0000x reference)
//
#include <hip/hip_runtime.h>
#include <cstddef>

#define BB 2
#define LL 1024
#define DM 768
#define DI 1536
#define NST 16
#define DTR 48
#define DINT 1536
#define NLAYER 2
#define ML (BB*LL)   /* 2048 rows */

static __device__ __forceinline__ float sigm(float x){ return 1.f/(1.f+__expf(-x)); }
static __device__ __forceinline__ float silu_(float x){ return x*sigm(x); }
static __device__ __forceinline__ float softplus_(float x){ return fmaxf(x,0.f)+log1pf(__expf(-fabsf(x))); }

// ---------------- embedding gather ----------------
__global__ void k_embed(const int* __restrict__ ids, const float* __restrict__ emb,
                        float* __restrict__ out){
  int idx = blockIdx.x*256 + threadIdx.x;
  if (idx >= ML*DM) return;
  int c = idx % DM; int bl = idx / DM;
  out[idx] = emb[(size_t)ids[bl]*DM + c];
}

// ---------------- c = a + b (b may be null -> copy) ----------------
__global__ void k_add(const float* __restrict__ a, const float* __restrict__ b,
                      float* __restrict__ c, int n){
  int idx = blockIdx.x*256 + threadIdx.x;
  if (idx >= n) return;
  c[idx] = b ? (a[idx] + b[idx]) : a[idx];
}

// ---------------- layernorm: one wave per 768-row; optional accumulate ----------------
__global__ __launch_bounds__(256) void k_ln(const float* __restrict__ x,
    const float* __restrict__ w, const float* __restrict__ bi,
    float* __restrict__ out, int acc){
  int wv = threadIdx.x >> 6, lane = threadIdx.x & 63;
  int row = blockIdx.x*4 + wv;
  if (row >= ML) return;
  const float* xr = x + (size_t)row*DM;
  float v[12]; float s = 0.f, sq = 0.f;
  #pragma unroll
  for (int i = 0; i < 12; i++){ v[i] = xr[lane + 64*i]; s += v[i]; sq += v[i]*v[i]; }
  #pragma unroll
  for (int o = 32; o; o >>= 1){ s += __shfl_xor(s, o, 64); sq += __shfl_xor(sq, o, 64); }
  float mean = s*(1.f/DM);
  float var  = sq*(1.f/DM) - mean*mean;
  float rstd = rsqrtf(var + 1e-5f);
  float* orow = out + (size_t)row*DM;
  #pragma unroll
  for (int i = 0; i < 12; i++){
    int c = lane + 64*i;
    float o = (v[i]-mean)*rstd*w[c] + bi[c];
    if (acc) o += orow[c];
    orow[c] = o;
  }
}

// ---------------- generic fp32 GEMM: C[M,N] = act(A[M,K(lda)] @ W[N,K]^T + bias + addsrc) ----------------
// act: 0=none, 1=softplus
__global__ __launch_bounds__(256) void k_gemm(const float* __restrict__ A, int lda,
    const float* __restrict__ W, const float* __restrict__ bias,
    const float* __restrict__ addsrc, float* __restrict__ C,
    int M, int N, int K, int act){
  __shared__ float As[16][68];   // pad to 68: 16B-aligned 4-float rows, <=2-way bank conflict
  __shared__ float Ws[16][68];
  int tid = threadIdx.x;
  int tx = tid & 15, ty = tid >> 4;
  int m0 = blockIdx.y*64, n0 = blockIdx.x*64;
  float acc[4][4] = {};
  for (int k0 = 0; k0 < K; k0 += 16){
    #pragma unroll
    for (int i = 0; i < 4; i++){
      int e = tid + 256*i;
      int r = e >> 4, c = e & 15;
      int gm = m0 + r, gk = k0 + c, gn = n0 + r;
      As[c][r] = (gm < M && gk < K) ? A[(size_t)gm*lda + gk] : 0.f;
      Ws[c][r] = (gn < N && gk < K) ? W[(size_t)gn*K + gk] : 0.f;
    }
    __syncthreads();
    #pragma unroll
    for (int kk = 0; kk < 16; kk++){
      float a[4], w[4];
      #pragma unroll
      for (int i = 0; i < 4; i++) a[i] = As[kk][ty*4+i];
      #pragma unroll
      for (int j = 0; j < 4; j++) w[j] = Ws[kk][tx*4+j];
      #pragma unroll
      for (int i = 0; i < 4; i++)
        #pragma unroll
        for (int j = 0; j < 4; j++) acc[i][j] += a[i]*w[j];
    }
    __syncthreads();
  }
  #pragma unroll
  for (int i = 0; i < 4; i++){
    int m = m0 + ty*4 + i; if (m >= M) continue;
    #pragma unroll
    for (int j = 0; j < 4; j++){
      int n = n0 + tx*4 + j; if (n >= N) continue;
      float v = acc[i][j];
      if (bias)   v += bias[n];
      if (addsrc) v += addsrc[(size_t)m*N + n];
      if (act == 1) v = softplus_(v);
      C[(size_t)m*N + n] = v;
    }
  }
}

// ---------------- depthwise causal conv (K=4) + silu; rev flips to anti-causal ----------------
__global__ void k_conv(const float* __restrict__ xz, const float* __restrict__ w,
                       const float* __restrict__ bi, float* __restrict__ out, int rev){
  int idx = blockIdx.x*256 + threadIdx.x;
  if (idx >= ML*DI) return;
  int d = idx % DI; int bl = idx / DI; int t = bl % LL; int b = bl / LL;
  float acc = bi[d];
  #pragma unroll
  for (int k = 0; k < 4; k++){
    int tp = rev ? (t + 3 - k) : (t - 3 + k);
    if (tp >= 0 && tp < LL)
      acc += w[d*4 + k] * xz[((size_t)(b*LL + tp))*(2*DI) + d];
  }
  out[idx] = silu_(acc);
}

// ---------------- selective scan, both directions; 16 lanes per (dir,b,d) channel ----------------
// y output aliases delta (safe: y[t] depends on delta[t], load precedes store; lockstep wave)
__global__ __launch_bounds__(256) void k_scan(
    const float* __restrict__ delta0, const float* __restrict__ delta1,
    const float* __restrict__ xc0, const float* __restrict__ xc1,
    const float* __restrict__ xd0, const float* __restrict__ xd1,
    const float* __restrict__ xz,
    const float* __restrict__ A_log, const float* __restrict__ Dp,
    float* __restrict__ y0, float* __restrict__ y1){
  int tid = blockIdx.x*256 + threadIdx.x;
  int n = tid & (NST-1);
  int cidx = tid >> 4;
  if (cidx >= 2*BB*DI) return;
  int d   = cidx % DI;
  int b   = (cidx / DI) % BB;
  int dir = cidx / (DI*BB);
  const float* delta = dir ? delta1 : delta0;
  const float* xc    = dir ? xc1 : xc0;
  const float* xd    = dir ? xd1 : xd0;
  float* y           = dir ? y1 : y0;
  float a  = -__expf(A_log[d*NST + n]);
  float dD = Dp[d];
  float h = 0.f;
  for (int t = 0; t < LL; t++){
    int tt = dir ? (LL-1-t) : t;
    size_t base = (size_t)(b*LL + tt);
    float de = delta[base*DI + d];
    float u  = xc[base*DI + d];
    float Bv = xd[base*80 + DTR + n];
    float Cv = xd[base*80 + DTR + NST + n];
    h = __expf(de*a)*h + (de*Bv)*u;
    float p = h*Cv;
    p += __shfl_xor(p, 1, 16);
    p += __shfl_xor(p, 2, 16);
    p += __shfl_xor(p, 4, 16);
    p += __shfl_xor(p, 8, 16);
    if (n == 0){
      float z = xz[base*(2*DI) + DI + d];
      y[base*DI + d] = (p + u*dD) * silu_(z);
    }
  }
}

// ---------------- MLP gating: g = y1 * silu(gate) from fc1 output (cols [0,1536) and [1536,3072)) ----------------
__global__ void k_gate(const float* __restrict__ fc1o, float* __restrict__ g){
  int idx = blockIdx.x*256 + threadIdx.x;
  if (idx >= ML*DINT) return;
  int i = idx % DINT; int bl = idx / DINT;
  float a  = fc1o[(size_t)bl*2*DINT + i];
  float gt = fc1o[(size_t)bl*2*DINT + DINT + i];
  g[idx] = a * silu_(gt);
}

// ---------------- mean over L ----------------
__global__ void k_mean(const float* __restrict__ x, float* __restrict__ out){
  int d = blockIdx.x*256 + threadIdx.x;
  int b = blockIdx.y;
  if (d >= DM) return;
  float s = 0.f;
  for (int t = 0; t < LL; t++) s += x[((size_t)(b*LL + t))*DM + d];
  out[b*DM + d] = s*(1.f/LL);
}

extern "C" void kernel_launch(void* const* d_in, const int* in_sizes, int n_in,
                              void* d_out, int out_size, void* d_ws, size_t ws_size,
                              hipStream_t stream){
  const int*   ids     = (const int*)d_in[0];
  const float* embed   = (const float*)d_in[1];
  const float* norm_w  = (const float*)d_in[2];
  const float* norm_b  = (const float*)d_in[3];
  const float* in_proj = (const float*)d_in[4];
  const float* conv_w  = (const float*)d_in[5];
  const float* conv_b  = (const float*)d_in[6];
  const float* x_proj  = (const float*)d_in[7];
  const float* dt_w    = (const float*)d_in[8];
  const float* dt_b    = (const float*)d_in[9];
  const float* A_log   = (const float*)d_in[10];
  const float* Dp      = (const float*)d_in[11];
  const float* out_pj  = (const float*)d_in[12];
  const float* norm2_w = (const float*)d_in[13];
  const float* norm2_b = (const float*)d_in[14];
  const float* fc1     = (const float*)d_in[15];
  const float* fc2     = (const float*)d_in[16];
  const float* normf_w = (const float*)d_in[17];
  const float* normf_b = (const float*)d_in[18];
  float* out = (float*)d_out;

  const size_t BLD   = (size_t)ML*DM;
  const size_t BLDI  = (size_t)ML*DI;
  const size_t BL80  = (size_t)ML*80;
  const size_t BL2DI = (size_t)ML*2*DI;

  float* ws = (float*)d_ws;
  size_t off = 0;
  float* h    = ws+off; off += BLD;
  float* res  = ws+off; off += BLD;
  float* rc   = ws+off; off += BLD;
  float* xln  = ws+off; off += BLD;
  float* x2   = ws+off; off += BLD;
  float* mlpo = ws+off; off += BLD;
  float* resd0= ws+off; off += BLD;
  float* resd1= ws+off; off += BLD;
  float* xz   = ws+off; off += BL2DI;   // also reused as fc1 output after scan
  float* xc0  = ws+off; off += BLDI;
  float* xc1  = ws+off; off += BLDI;
  float* dl0  = ws+off; off += BLDI;    // delta dir0; y dir0 aliases it
  float* dl1  = ws+off; off += BLDI;
  float* g    = ws+off; off += BLDI;
  float* xd0  = ws+off; off += BL80;
  float* xd1  = ws+off; off += BL80;
  (void)ws_size; (void)in_sizes; (void)n_in; (void)out_size;

  dim3 blk(256);
  auto cdiv = [](int a, int b){ return (a + b - 1)/b; };

  k_embed<<<cdiv(ML*DM,256), blk, 0, stream>>>(ids, embed, h);

  for (int l = 0; l < NLAYER; l++){
    const float* nw  = norm_w  + l*DM;
    const float* nb  = norm_b  + l*DM;
    const float* ip  = in_proj + (size_t)l*2*DI*DM;
    const float* cw  = conv_w  + (size_t)l*DI*4;
    const float* cb  = conv_b  + (size_t)l*DI;
    const float* xp  = x_proj  + (size_t)l*(DTR+2*NST)*DI;
    const float* dw  = dt_w    + (size_t)l*DI*DTR;
    const float* db  = dt_b    + (size_t)l*DI;
    const float* al  = A_log   + (size_t)l*DI*NST;
    const float* dpl = Dp      + (size_t)l*DI;
    const float* op  = out_pj  + (size_t)l*DM*DI;
    const float* n2w = norm2_w + l*DM;
    const float* n2b = norm2_b + l*DM;
    const float* f1  = fc1 + (size_t)l*2*DINT*DM;
    const float* f2  = fc2 + (size_t)l*DM*DINT;

    // rc = h (+ res); shared prologue of both directions
    k_add<<<cdiv(ML*DM,256), blk, 0, stream>>>(h, (l==0)?nullptr:res, rc, ML*DM);
    k_ln<<<ML/4, blk, 0, stream>>>(rc, nw, nb, xln, 0);
    // xz = xln @ in_proj^T  (shared between directions; reversal commutes with row-wise ops)
    k_gemm<<<dim3(cdiv(2*DI,64), cdiv(ML,64)), blk, 0, stream>>>(xln, DM, ip, nullptr, nullptr, xz, ML, 2*DI, DM, 0);
    // conv (fwd causal / bwd anti-causal) + silu
    k_conv<<<cdiv(ML*DI,256), blk, 0, stream>>>(xz, cw, cb, xc0, 0);
    k_conv<<<cdiv(ML*DI,256), blk, 0, stream>>>(xz, cw, cb, xc1, 1);
    // x_dbl = xc @ x_proj^T  (N=80)
    k_gemm<<<dim3(cdiv(80,64), cdiv(ML,64)), blk, 0, stream>>>(xc0, DI, xp, nullptr, nullptr, xd0, ML, 80, DI, 0);
    k_gemm<<<dim3(cdiv(80,64), cdiv(ML,64)), blk, 0, stream>>>(xc1, DI, xp, nullptr, nullptr, xd1, ML, 80, DI, 0);
    // delta = softplus(dt @ dt_w^T + dt_b)  (A = x_dbl cols [0,48), lda=80)
    k_gemm<<<dim3(cdiv(DI,64), cdiv(ML,64)), blk, 0, stream>>>(xd0, 80, dw, db, nullptr, dl0, ML, DI, DTR, 1);
    k_gemm<<<dim3(cdiv(DI,64), cdiv(ML,64)), blk, 0, stream>>>(xd1, 80, dw, db, nullptr, dl1, ML, DI, DTR, 1);
    // selective scan both dirs, fused * silu(z); y aliases delta
    k_scan<<<(2*BB*DI*16)/256, blk, 0, stream>>>(dl0, dl1, xc0, xc1, xd0, xd1, xz, al, dpl, dl0, dl1);
    // res_dir = y @ out_proj^T + rc
    k_gemm<<<dim3(cdiv(DM,64), cdiv(ML,64)), blk, 0, stream>>>(dl0, DI, op, nullptr, rc, resd0, ML, DM, DI, 0);
    k_gemm<<<dim3(cdiv(DM,64), cdiv(ML,64)), blk, 0, stream>>>(dl1, DI, op, nullptr, rc, resd1, ML, DM, DI, 0);
    // MLP per direction, h = LN_f(mlp_f) + LN_f(mlp_b)
    for (int dir = 0; dir < 2; dir++){
      float* rd = dir ? resd1 : resd0;
      k_ln<<<ML/4, blk, 0, stream>>>(rd, n2w, n2b, x2, 0);
      k_gemm<<<dim3(cdiv(2*DINT,64), cdiv(ML,64)), blk, 0, stream>>>(x2, DM, f1, nullptr, nullptr, xz, ML, 2*DINT, DM, 0);
      k_gate<<<cdiv(ML*DINT,256), blk, 0, stream>>>(xz, g);
      k_gemm<<<dim3(cdiv(DM,64), cdiv(ML,64)), blk, 0, stream>>>(g, DINT, f2, nullptr, nullptr, mlpo, ML, DM, DINT, 0);
      k_ln<<<ML/4, blk, 0, stream>>>(mlpo, normf_w, normf_b, h, dir);
    }
    // res = resd0 + resd1
    k_add<<<cdiv(ML*DM,256), blk, 0, stream>>>(resd0, resd1, res, ML*DM);
  }

  // final: res = h + res; h = LN_f(res); out = mean over L
  k_add<<<cdiv(ML*DM,256), blk, 0, stream>>>(h, res, rc, ML*DM);
  k_ln<<<ML/4, blk, 0, stream>>>(rc, normf_w, normf_b, xln, 0);
  k_mean<<<dim3(3, BB), blk, 0, stream>>>(xln, out);
}

// Round 2
// 2763.914 us; speedup vs baseline: 1.9641x; 1.9641x over previous
//
#include <hip/hip_runtime.h>
#include <cstddef>

#define BB 2
#define LL 1024
#define DM 768
#define DI 1536
#define NST 16
#define DTR 48
#define DINT 1536
#define NLAYER 2
#define ML (BB*LL)   /* 2048 rows */

typedef __attribute__((ext_vector_type(8))) short s16x8;
typedef __attribute__((ext_vector_type(4))) float f32x4;

static __device__ __forceinline__ float sigm(float x){ return 1.f/(1.f+__expf(-x)); }
static __device__ __forceinline__ float silu_(float x){ return x*sigm(x); }
static __device__ __forceinline__ float softplus_(float x){ return fmaxf(x,0.f)+log1pf(__expf(-fabsf(x))); }
// fp32 -> bf16 bits, round-to-nearest-even
static __device__ __forceinline__ unsigned short f2b(float x){
  unsigned int u = __float_as_uint(x);
  unsigned int r = (u + 0x7fffu + ((u>>16)&1u)) >> 16;
  return (unsigned short)r;
}

// ---------------- embedding gather ----------------
__global__ void k_embed(const int* __restrict__ ids, const float* __restrict__ emb,
                        float* __restrict__ out){
  int idx = blockIdx.x*256 + threadIdx.x;
  if (idx >= ML*DM) return;
  int c = idx % DM; int bl = idx / DM;
  out[idx] = emb[(size_t)ids[bl]*DM + c];
}

// ---------------- c = a + b (b may be null -> copy) ----------------
__global__ void k_add(const float* __restrict__ a, const float* __restrict__ b,
                      float* __restrict__ c, int n){
  int idx = blockIdx.x*256 + threadIdx.x;
  if (idx >= n) return;
  c[idx] = b ? (a[idx] + b[idx]) : a[idx];
}

// ---------------- fp32 -> bf16 convert ----------------
__global__ void k_f2b(const float* __restrict__ in, unsigned short* __restrict__ out, int n){
  int idx = blockIdx.x*256 + threadIdx.x;
  if (idx >= n) return;
  out[idx] = f2b(in[idx]);
}

// ---------------- W_eff = dt_w @ x_proj[:48]  -> bf16 into wbig rows [0,1536) ----------------
__global__ void k_weff(const float* __restrict__ dw, const float* __restrict__ xp,
                       unsigned short* __restrict__ wbig){
  int idx = blockIdx.x*256 + threadIdx.x;  // over 1536*1536
  int j = idx % DI, i = idx / DI;
  float s = 0.f;
  #pragma unroll
  for (int k = 0; k < DTR; k++) s += dw[i*DTR + k] * xp[(size_t)k*DI + j];
  wbig[idx] = f2b(s);
}

// ---------------- wbig rows [1536,1664): copy x_proj[48:80] (bf16), zero-pad rest ----------------
__global__ void k_wtail(const float* __restrict__ xp, unsigned short* __restrict__ wbig){
  int idx = blockIdx.x*256 + threadIdx.x;  // over 128*1536
  if (idx >= 128*DI) return;
  int j = idx % DI, r = idx / DI;
  unsigned short v = (r < 32) ? f2b(xp[(size_t)(DTR + r)*DI + j]) : (unsigned short)0;
  wbig[(size_t)(DI + r)*DI + j] = v;
}

// ---------------- layernorm: one wave per 768-row; fp32 out (optional, acc) + bf16 out (optional) ----------------
__global__ __launch_bounds__(256) void k_ln(const float* __restrict__ x,
    const float* __restrict__ w, const float* __restrict__ bi,
    float* __restrict__ fout, unsigned short* __restrict__ bout, int acc){
  int wv = threadIdx.x >> 6, lane = threadIdx.x & 63;
  int row = blockIdx.x*4 + wv;
  if (row >= ML) return;
  const float* xr = x + (size_t)row*DM;
  float v[12]; float s = 0.f, sq = 0.f;
  #pragma unroll
  for (int i = 0; i < 12; i++){ v[i] = xr[lane + 64*i]; s += v[i]; sq += v[i]*v[i]; }
  #pragma unroll
  for (int o = 32; o; o >>= 1){ s += __shfl_xor(s, o, 64); sq += __shfl_xor(sq, o, 64); }
  float mean = s*(1.f/DM);
  float var  = sq*(1.f/DM) - mean*mean;
  float rstd = rsqrtf(var + 1e-5f);
  #pragma unroll
  for (int i = 0; i < 12; i++){
    int c = lane + 64*i;
    float o = (v[i]-mean)*rstd*w[c] + bi[c];
    if (fout){
      float oo = o;
      if (acc) oo += fout[(size_t)row*DM + c];
      fout[(size_t)row*DM + c] = oo;
    }
    if (bout) bout[(size_t)row*DM + c] = f2b(o);
  }
}

// ---------------- bf16 MFMA GEMM: C[2048,N] = A[2048,K]bf16 @ W[N,K]bf16^T (+addsrc) ----------------
// 128x128 tile, BK=32, 4 waves (2x2), 16 acc frags/wave. N,K multiples of 128/32; M=2048.
// mode 0: C = acc (+ addsrc).  mode 1 (delta/BC fused): n<1536 -> delta=softplus(acc+dtb[n]);
//                              1536<=n<1568 -> bcout[m*32+(n-1536)] = acc; else drop (zero-padded W).
__global__ __launch_bounds__(256) void k_mgemm(const unsigned short* __restrict__ A,
    const unsigned short* __restrict__ W, const float* __restrict__ addsrc,
    float* __restrict__ C, int N, int K, int mode,
    const float* __restrict__ dtb, float* __restrict__ delta, float* __restrict__ bcout){
  __shared__ __align__(16) unsigned short As[4096], Bs[4096];  // 8 mtiles x 64 lanes x 8 bf16
  int t = threadIdx.x;
  int m0 = blockIdx.y*128, n0 = blockIdx.x*128;
  int lane = t & 63, w = t >> 6;
  int wm = w & 1, wn = w >> 1;
  f32x4 acc[4][4] = {};
  for (int k0 = 0; k0 < K; k0 += 32){
    #pragma unroll
    for (int si = 0; si < 2; si++){
      int s = t + si*256;                 // slot: mt=s>>6, lane L=s&63
      int row = ((s>>6)<<4) + (s & 15);   // mt*16 + (L&15)
      int ko  = ((s>>4) & 3) << 3;        // (L>>4)*8
      *(uint4*)&As[s*8] = *(const uint4*)&A[(size_t)(m0+row)*K + k0 + ko];
      *(uint4*)&Bs[s*8] = *(const uint4*)&W[(size_t)(n0+row)*K + k0 + ko];
    }
    __syncthreads();
    s16x8 af[4], bf[4];
    #pragma unroll
    for (int i = 0; i < 4; i++) af[i] = *(const s16x8*)&As[((wm*4+i)*64 + lane)*8];
    #pragma unroll
    for (int j = 0; j < 4; j++) bf[j] = *(const s16x8*)&Bs[((wn*4+j)*64 + lane)*8];
    #pragma unroll
    for (int i = 0; i < 4; i++)
      #pragma unroll
      for (int j = 0; j < 4; j++)
        acc[i][j] = __builtin_amdgcn_mfma_f32_16x16x32_bf16(af[i], bf[j], acc[i][j], 0, 0, 0);
    __syncthreads();
  }
  // epilogue: C/D layout col=lane&15, row=(lane>>4)*4+reg
  int cl = lane & 15, qd = lane >> 4;
  #pragma unroll
  for (int i = 0; i < 4; i++){
    int mbase = m0 + (wm*4+i)*16 + qd*4;
    #pragma unroll
    for (int j = 0; j < 4; j++){
      int n = n0 + (wn*4+j)*16 + cl;
      #pragma unroll
      for (int r = 0; r < 4; r++){
        int m = mbase + r;
        float v = acc[i][j][r];
        if (mode == 0){
          if (addsrc) v += addsrc[(size_t)m*N + n];
          C[(size_t)m*N + n] = v;
        } else {
          if (n < DI) delta[(size_t)m*DI + n] = softplus_(v + dtb[n]);
          else if (n < DI + 32) bcout[(size_t)m*32 + (n - DI)] = v;
        }
      }
    }
  }
}

// ---------------- depthwise causal conv (K=4) + silu; fp32 + bf16 outputs ----------------
__global__ void k_conv(const float* __restrict__ xz, const float* __restrict__ w,
                       const float* __restrict__ bi, float* __restrict__ xc,
                       unsigned short* __restrict__ xcb, int rev){
  int idx = blockIdx.x*256 + threadIdx.x;
  if (idx >= ML*DI) return;
  int d = idx % DI; int bl = idx / DI; int t = bl % LL; int b = bl / LL;
  float acc = bi[d];
  #pragma unroll
  for (int k = 0; k < 4; k++){
    int tp = rev ? (t + 3 - k) : (t - 3 + k);
    if (tp >= 0 && tp < LL)
      acc += w[d*4 + k] * xz[((size_t)(b*LL + tp))*(2*DI) + d];
  }
  float v = silu_(acc);
  xc[idx]  = v;
  xcb[idx] = f2b(v);
}

// ---------------- selective scan, both dirs, prefetched; y out bf16 ----------------
__global__ __launch_bounds__(256) void k_scan(
    const float* __restrict__ delta0, const float* __restrict__ delta1,
    const float* __restrict__ xc0, const float* __restrict__ xc1,
    const float* __restrict__ bc0, const float* __restrict__ bc1,
    const float* __restrict__ xz,
    const float* __restrict__ A_log, const float* __restrict__ Dp,
    unsigned short* __restrict__ y0, unsigned short* __restrict__ y1){
  int tid = blockIdx.x*256 + threadIdx.x;
  int n = tid & (NST-1);
  int cidx = tid >> 4;
  if (cidx >= 2*BB*DI) return;
  int d   = cidx % DI;
  int b   = (cidx / DI) % BB;
  int dir = cidx / (DI*BB);
  const float* delta = dir ? delta1 : delta0;
  const float* xc    = dir ? xc1 : xc0;
  const float* bc    = dir ? bc1 : bc0;
  unsigned short* y  = dir ? y1 : y0;
  float a  = -__expf(A_log[d*NST + n]);
  float dD = Dp[d];
  float h = 0.f;
  int step = dir ? -1 : 1;
  size_t base = (size_t)(b*LL + (dir ? LL-1 : 0));
  float de = delta[base*DI + d];
  float u  = xc[base*DI + d];
  float Bv = bc[base*32 + n];
  float Cv = bc[base*32 + 16 + n];
  float z  = (n == 0) ? xz[base*(2*DI) + DI + d] : 0.f;
  for (int t = 0; t < LL; t++){
    size_t nbase = base + step;
    float de2 = 0.f, u2 = 0.f, Bv2 = 0.f, Cv2 = 0.f, z2 = 0.f;
    if (t + 1 < LL){   // prefetch next timestep before the dependent chain
      de2 = delta[nbase*DI + d];
      u2  = xc[nbase*DI + d];
      Bv2 = bc[nbase*32 + n];
      Cv2 = bc[nbase*32 + 16 + n];
      if (n == 0) z2 = xz[nbase*(2*DI) + DI + d];
    }
    h = __expf(de*a)*h + (de*Bv)*u;
    float p = h*Cv;
    p += __shfl_xor(p, 1, 16);
    p += __shfl_xor(p, 2, 16);
    p += __shfl_xor(p, 4, 16);
    p += __shfl_xor(p, 8, 16);
    if (n == 0) y[base*DI + d] = f2b((p + u*dD) * silu_(z));
    de = de2; u = u2; Bv = Bv2; Cv = Cv2; z = z2; base = nbase;
  }
}

// ---------------- MLP gating -> bf16 ----------------
__global__ void k_gate(const float* __restrict__ fc1o, unsigned short* __restrict__ g){
  int idx = blockIdx.x*256 + threadIdx.x;
  if (idx >= ML*DINT) return;
  int i = idx % DINT; int bl = idx / DINT;
  float a  = fc1o[(size_t)bl*2*DINT + i];
  float gt = fc1o[(size_t)bl*2*DINT + DINT + i];
  g[idx] = f2b(a * silu_(gt));
}

// ---------------- mean over L ----------------
__global__ void k_mean(const float* __restrict__ x, float* __restrict__ out){
  int d = blockIdx.x*256 + threadIdx.x;
  int b = blockIdx.y;
  if (d >= DM) return;
  float s = 0.f;
  for (int t = 0; t < LL; t++) s += x[((size_t)(b*LL + t))*DM + d];
  out[b*DM + d] = s*(1.f/LL);
}

extern "C" void kernel_launch(void* const* d_in, const int* in_sizes, int n_in,
                              void* d_out, int out_size, void* d_ws, size_t ws_size,
                              hipStream_t stream){
  const int*   ids     = (const int*)d_in[0];
  const float* embed   = (const float*)d_in[1];
  const float* norm_w  = (const float*)d_in[2];
  const float* norm_b  = (const float*)d_in[3];
  const float* in_proj = (const float*)d_in[4];
  const float* conv_w  = (const float*)d_in[5];
  const float* conv_b  = (const float*)d_in[6];
  const float* x_proj  = (const float*)d_in[7];
  const float* dt_w    = (const float*)d_in[8];
  const float* dt_b    = (const float*)d_in[9];
  const float* A_log   = (const float*)d_in[10];
  const float* Dp      = (const float*)d_in[11];
  const float* out_pj  = (const float*)d_in[12];
  const float* norm2_w = (const float*)d_in[13];
  const float* norm2_b = (const float*)d_in[14];
  const float* fc1     = (const float*)d_in[15];
  const float* fc2     = (const float*)d_in[16];
  const float* normf_w = (const float*)d_in[17];
  const float* normf_b = (const float*)d_in[18];
  float* out = (float*)d_out;

  const size_t BLD   = (size_t)ML*DM;       // 1,572,864
  const size_t BLDI  = (size_t)ML*DI;       // 3,145,728
  const size_t BL2DI = (size_t)ML*2*DI;     // 6,291,456

  // fp32 arena
  float* f = (float*)d_ws; size_t off = 0;
  float* h     = f+off; off += BLD;
  float* res   = f+off; off += BLD;
  float* rc    = f+off; off += BLD;
  float* resd0 = f+off; off += BLD;
  float* resd1 = f+off; off += BLD;
  float* xz    = f+off; off += BL2DI;
  float* xc0   = f+off; off += BLDI;
  float* xc1   = f+off; off += BLDI;
  float* dl0   = f+off; off += BLDI;
  float* dl1   = f+off; off += BLDI;
  float* xdbc0 = f+off; off += (size_t)ML*32;
  float* xdbc1 = f+off; off += (size_t)ML*32;
  // aliases into free fp32 regions during the MLP phase (scan has consumed dl*)
  float*          mlpo = dl1;
  unsigned short* gb   = (unsigned short*)dl0;
  // bf16 arena
  unsigned short* u16 = (unsigned short*)(f + off); size_t uo = 0;
  unsigned short* xlnb = u16+uo; uo += BLD;            // x2b aliases
  unsigned short* x2b  = xlnb;
  unsigned short* xcb0 = u16+uo; uo += BLDI;           // yb0 aliases
  unsigned short* xcb1 = u16+uo; uo += BLDI;           // yb1 aliases
  unsigned short* yb0  = xcb0;
  unsigned short* yb1  = xcb1;
  unsigned short* wib  = u16+uo; uo += (size_t)2*DI*DM;   // wf1b aliases (after in_proj GEMM)
  unsigned short* wob  = u16+uo; uo += (size_t)DM*DI;     // wf2b aliases (after out_proj GEMMs)
  unsigned short* wf1b = wib;
  unsigned short* wf2b = wob;
  unsigned short* wbig = u16+uo; uo += (size_t)1664*DI;
  (void)ws_size; (void)in_sizes; (void)n_in; (void)out_size;

  dim3 blk(256);
  auto cdiv = [](int a, int b){ return (a + b - 1)/b; };

  k_embed<<<cdiv(ML*DM,256), blk, 0, stream>>>(ids, embed, h);

  for (int l = 0; l < NLAYER; l++){
    const float* nw  = norm_w  + l*DM;
    const float* nb  = norm_b  + l*DM;
    const float* ip  = in_proj + (size_t)l*2*DI*DM;
    const float* cw  = conv_w  + (size_t)l*DI*4;
    const float* cb  = conv_b  + (size_t)l*DI;
    const float* xp  = x_proj  + (size_t)l*(DTR+2*NST)*DI;
    const float* dw  = dt_w    + (size_t)l*DI*DTR;
    const float* db  = dt_b    + (size_t)l*DI;
    const float* al  = A_log   + (size_t)l*DI*NST;
    const float* dpl = Dp      + (size_t)l*DI;
    const float* op  = out_pj  + (size_t)l*DM*DI;
    const float* n2w = norm2_w + l*DM;
    const float* n2b = norm2_b + l*DM;
    const float* f1  = fc1 + (size_t)l*2*DINT*DM;
    const float* f2  = fc2 + (size_t)l*DM*DINT;

    // per-layer weight prep
    k_f2b<<<cdiv(2*DI*DM,256), blk, 0, stream>>>(ip, wib, 2*DI*DM);
    k_f2b<<<cdiv(DM*DI,256), blk, 0, stream>>>(op, wob, DM*DI);
    k_weff<<<cdiv(DI*DI,256), blk, 0, stream>>>(dw, xp, wbig);
    k_wtail<<<cdiv(128*DI,256), blk, 0, stream>>>(xp, wbig);

    // shared prologue (reversal commutes with row-wise ops)
    k_add<<<cdiv(ML*DM,256), blk, 0, stream>>>(h, (l==0)?nullptr:res, rc, ML*DM);
    k_ln<<<ML/4, blk, 0, stream>>>(rc, nw, nb, nullptr, xlnb, 0);
    // xz = xln @ in_proj^T
    k_mgemm<<<dim3(2*DI/128, ML/128), blk, 0, stream>>>(xlnb, wib, nullptr, xz, 2*DI, DM, 0, nullptr, nullptr, nullptr);
    // conv (causal / anti-causal) + silu
    k_conv<<<cdiv(ML*DI,256), blk, 0, stream>>>(xz, cw, cb, xc0, xcb0, 0);
    k_conv<<<cdiv(ML*DI,256), blk, 0, stream>>>(xz, cw, cb, xc1, xcb1, 1);
    // fused delta/B/C GEMM per dir: [delta | B C | pad] = xc @ wbig^T
    k_mgemm<<<dim3(1664/128, ML/128), blk, 0, stream>>>(xcb0, wbig, nullptr, nullptr, 1664, DI, 1, db, dl0, xdbc0);
    k_mgemm<<<dim3(1664/128, ML/128), blk, 0, stream>>>(xcb1, wbig, nullptr, nullptr, 1664, DI, 1, db, dl1, xdbc1);
    // selective scan both dirs (fused * silu(z)); y -> bf16 (aliases xcb)
    k_scan<<<(2*BB*DI*16)/256, blk, 0, stream>>>(dl0, dl1, xc0, xc1, xdbc0, xdbc1, xz, al, dpl, yb0, yb1);
    // fc1 weights into wib region (in_proj GEMM is done)
    k_f2b<<<cdiv(2*DINT*DM,256), blk, 0, stream>>>(f1, wf1b, 2*DINT*DM);
    // res_dir = y @ out_proj^T + rc
    k_mgemm<<<dim3(DM/128, ML/128), blk, 0, stream>>>(yb0, wob, rc, resd0, DM, DI, 0, nullptr, nullptr, nullptr);
    k_mgemm<<<dim3(DM/128, ML/128), blk, 0, stream>>>(yb1, wob, rc, resd1, DM, DI, 0, nullptr, nullptr, nullptr);
    // fc2 weights into wob region (out_proj GEMMs are done)
    k_f2b<<<cdiv(DM*DINT,256), blk, 0, stream>>>(f2, wf2b, DM*DINT);
    // MLP per direction; h = LN_f(mlp_f) + LN_f(mlp_b)
    for (int dir = 0; dir < 2; dir++){
      float* rd = dir ? resd1 : resd0;
      k_ln<<<ML/4, blk, 0, stream>>>(rd, n2w, n2b, nullptr, x2b, 0);
      k_mgemm<<<dim3(2*DINT/128, ML/128), blk, 0, stream>>>(x2b, wf1b, nullptr, xz, 2*DINT, DM, 0, nullptr, nullptr, nullptr);
      k_gate<<<cdiv(ML*DINT,256), blk, 0, stream>>>(xz, gb);
      k_mgemm<<<dim3(DM/128, ML/128), blk, 0, stream>>>(gb, wf2b, nullptr, mlpo, DM, DINT, 0, nullptr, nullptr, nullptr);
      k_ln<<<ML/4, blk, 0, stream>>>(mlpo, normf_w, normf_b, h, nullptr, dir);
    }
    // res = resd0 + resd1
    k_add<<<cdiv(ML*DM,256), blk, 0, stream>>>(resd0, resd1, res, ML*DM);
  }

  // final: rc = h + res; LN -> resd0; mean over L
  k_add<<<cdiv(ML*DM,256), blk, 0, stream>>>(h, res, rc, ML*DM);
  k_ln<<<ML/4, blk, 0, stream>>>(rc, normf_w, normf_b, resd0, nullptr, 0);
  k_mean<<<dim3(3, BB), blk, 0, stream>>>(resd0, out);
}

// Round 3
// 1811.581 us; speedup vs baseline: 2.9966x; 1.5257x over previous
//
#include <hip/hip_runtime.h>
#include <cstddef>

#define BB 2
#define LL 1024
#define DM 768
#define DI 1536
#define NST 16
#define DTR 48
#define DINT 1536
#define NLAYER 2
#define ML (BB*LL)      /* 2048 rows per direction */
#define NCH 16
#define CLEN (LL/NCH)   /* 64 */

typedef __attribute__((ext_vector_type(8))) short s16x8;
typedef __attribute__((ext_vector_type(4))) float f32x4;

static __device__ __forceinline__ float sigm(float x){ return 1.f/(1.f+__expf(-x)); }
static __device__ __forceinline__ float silu_(float x){ return x*sigm(x); }
static __device__ __forceinline__ float softplus_(float x){ return fmaxf(x,0.f)+log1pf(__expf(-fabsf(x))); }
static __device__ __forceinline__ unsigned short f2b(float x){
  unsigned int u = __float_as_uint(x);
  unsigned int r = (u + 0x7fffu + ((u>>16)&1u)) >> 16;
  return (unsigned short)r;
}
static __device__ __forceinline__ float b2f(unsigned short v){
  return __uint_as_float(((unsigned int)v) << 16);
}

// ---------------- embedding gather ----------------
__global__ void k_embed(const int* __restrict__ ids, const float* __restrict__ emb,
                        float* __restrict__ out){
  int idx = blockIdx.x*256 + threadIdx.x;
  if (idx >= ML*DM) return;
  int c = idx % DM; int bl = idx / DM;
  out[idx] = emb[(size_t)ids[bl]*DM + c];
}

// ---------------- c = a + b ----------------
__global__ void k_add(const float* __restrict__ a, const float* __restrict__ b,
                      float* __restrict__ c, int n){
  int idx = blockIdx.x*256 + threadIdx.x;
  if (idx >= n) return;
  c[idx] = a[idx] + b[idx];
}

// ---------------- fp32 -> bf16 convert ----------------
__global__ void k_f2b(const float* __restrict__ in, unsigned short* __restrict__ out, int n){
  int idx = blockIdx.x*256 + threadIdx.x;
  if (idx >= n) return;
  out[idx] = f2b(in[idx]);
}

// ---------------- W_eff = dt_w @ x_proj[:48]  -> bf16 into wbig rows [0,1536) ----------------
__global__ void k_weff(const float* __restrict__ dw, const float* __restrict__ xp,
                       unsigned short* __restrict__ wbig){
  int idx = blockIdx.x*256 + threadIdx.x;  // over 1536*1536
  int j = idx % DI, i = idx / DI;
  float s = 0.f;
  #pragma unroll
  for (int k = 0; k < DTR; k++) s += dw[i*DTR + k] * xp[(size_t)k*DI + j];
  wbig[idx] = f2b(s);
}

// ---------------- wbig rows [1536,1664): x_proj[48:80] bf16, zero-pad rest ----------------
__global__ void k_wtail(const float* __restrict__ xp, unsigned short* __restrict__ wbig){
  int idx = blockIdx.x*256 + threadIdx.x;  // over 128*1536
  if (idx >= 128*DI) return;
  int j = idx % DI, r = idx / DI;
  unsigned short v = (r < 32) ? f2b(xp[(size_t)(DTR + r)*DI + j]) : (unsigned short)0;
  wbig[(size_t)(DI + r)*DI + j] = v;
}

// ---------------- layernorm (one wave per 768-row), fused pre-add + optional outputs ----------------
// v = x + add; sumout <- v (pre-LN); fout <- LN(v) (+= if acc); bout <- bf16(LN(v))
__global__ __launch_bounds__(256) void k_ln(const float* __restrict__ x,
    const float* __restrict__ add, const float* __restrict__ w, const float* __restrict__ bi,
    float* __restrict__ sumout, float* __restrict__ fout, unsigned short* __restrict__ bout,
    int acc, int rows){
  int wv = threadIdx.x >> 6, lane = threadIdx.x & 63;
  int row = blockIdx.x*4 + wv;
  if (row >= rows) return;
  const float* xr = x + (size_t)row*DM;
  float v[12]; float s = 0.f, sq = 0.f;
  #pragma unroll
  for (int i = 0; i < 12; i++){
    int c = lane + 64*i;
    float t = xr[c];
    if (add) t += add[(size_t)row*DM + c];
    if (sumout) sumout[(size_t)row*DM + c] = t;
    v[i] = t; s += t; sq += t*t;
  }
  #pragma unroll
  for (int o = 32; o; o >>= 1){ s += __shfl_xor(s, o, 64); sq += __shfl_xor(sq, o, 64); }
  float mean = s*(1.f/DM);
  float var  = sq*(1.f/DM) - mean*mean;
  float rstd = rsqrtf(var + 1e-5f);
  #pragma unroll
  for (int i = 0; i < 12; i++){
    int c = lane + 64*i;
    float o = (v[i]-mean)*rstd*w[c] + bi[c];
    if (fout){
      float oo = o;
      if (acc) oo += fout[(size_t)row*DM + c];
      fout[(size_t)row*DM + c] = oo;
    }
    if (bout) bout[(size_t)row*DM + c] = f2b(o);
  }
}

// ---------------- bf16 MFMA GEMM: [M x N] = A[M,K] @ W[N,K]^T ----------------
// mode 0: Cf = acc (+ addsrc[m & 2047]); mode 2: Cb = bf16(acc)
// mode 1: n<1536 -> dlb = bf16(softplus(acc+dtb[n])); 1536<=n<1568 -> bcout[m*32+(n-1536)] = acc
__global__ __launch_bounds__(256) void k_mgemm(const unsigned short* __restrict__ A,
    const unsigned short* __restrict__ W, const float* __restrict__ addsrc,
    float* __restrict__ Cf, unsigned short* __restrict__ Cb, int N, int K, int mode,
    const float* __restrict__ dtb, unsigned short* __restrict__ dlb, float* __restrict__ bcout){
  __shared__ __align__(16) unsigned short As[4096], Bs[4096];
  int t = threadIdx.x;
  int m0 = blockIdx.y*128, n0 = blockIdx.x*128;
  int lane = t & 63, w = t >> 6;
  int wm = w & 1, wn = w >> 1;
  f32x4 acc[4][4] = {};
  for (int k0 = 0; k0 < K; k0 += 32){
    #pragma unroll
    for (int si = 0; si < 2; si++){
      int s = t + si*256;
      int row = ((s>>6)<<4) + (s & 15);
      int ko  = ((s>>4) & 3) << 3;
      *(uint4*)&As[s*8] = *(const uint4*)&A[(size_t)(m0+row)*K + k0 + ko];
      *(uint4*)&Bs[s*8] = *(const uint4*)&W[(size_t)(n0+row)*K + k0 + ko];
    }
    __syncthreads();
    s16x8 af[4], bf[4];
    #pragma unroll
    for (int i = 0; i < 4; i++) af[i] = *(const s16x8*)&As[((wm*4+i)*64 + lane)*8];
    #pragma unroll
    for (int j = 0; j < 4; j++) bf[j] = *(const s16x8*)&Bs[((wn*4+j)*64 + lane)*8];
    #pragma unroll
    for (int i = 0; i < 4; i++)
      #pragma unroll
      for (int j = 0; j < 4; j++)
        acc[i][j] = __builtin_amdgcn_mfma_f32_16x16x32_bf16(af[i], bf[j], acc[i][j], 0, 0, 0);
    __syncthreads();
  }
  int cl = lane & 15, qd = lane >> 4;
  #pragma unroll
  for (int i = 0; i < 4; i++){
    int mbase = m0 + (wm*4+i)*16 + qd*4;
    #pragma unroll
    for (int j = 0; j < 4; j++){
      int n = n0 + (wn*4+j)*16 + cl;
      #pragma unroll
      for (int r = 0; r < 4; r++){
        int m = mbase + r;
        float v = acc[i][j][r];
        if (mode == 0){
          if (addsrc) v += addsrc[(size_t)(m & (ML-1))*N + n];
          Cf[(size_t)m*N + n] = v;
        } else if (mode == 2){
          Cb[(size_t)m*N + n] = f2b(v);
        } else {
          if (n < DI) dlb[(size_t)m*DI + n] = f2b(softplus_(v + dtb[n]));
          else if (n < DI + 32) bcout[(size_t)m*32 + (n - DI)] = v;
        }
      }
    }
  }
}

// ---------------- depthwise conv (K=4, causal fwd / anti-causal bwd) + silu -> bf16 ----------------
__global__ void k_conv(const float* __restrict__ xz, const float* __restrict__ w,
                       const float* __restrict__ bi, unsigned short* __restrict__ xcb){
  int idx = blockIdx.x*256 + threadIdx.x;   // over 2*ML*DI
  if (idx >= 2*ML*DI) return;
  int d = idx % DI; int r = idx / DI;
  int bl = r % ML; int dir = r / ML;
  int t = bl % LL; int b = bl / LL;
  float acc = bi[d];
  #pragma unroll
  for (int k = 0; k < 4; k++){
    int tp = dir ? (t + 3 - k) : (t - 3 + k);
    if (tp >= 0 && tp < LL)
      acc += w[d*4 + k] * xz[((size_t)(b*LL + tp))*(2*DI) + d];
  }
  xcb[idx] = f2b(silu_(acc));
}

// ---------------- scan phase 1: per-chunk summaries (Aprod, h_end) ----------------
__global__ __launch_bounds__(256) void k_scan1(
    const unsigned short* __restrict__ dlb, const unsigned short* __restrict__ xcb,
    const float* __restrict__ bc, const float* __restrict__ A_log,
    float* __restrict__ sA, float* __restrict__ sH){
  int gid = blockIdx.x*256 + threadIdx.x;   // 2*BB*NCH*DI*16 threads
  int n = gid & 15;
  int rest = gid >> 4;
  int d = rest % DI; rest /= DI;
  int ch = rest % NCH; rest /= NCH;
  int b = rest & 1; int dir = rest >> 1;
  float a = -__expf(A_log[d*NST + n]);
  int step = dir ? -1 : 1;
  int tt = dir ? (LL-1 - ch*CLEN) : ch*CLEN;
  size_t row = (size_t)dir*ML + b*LL + tt;
  float h = 0.f, P = 1.f;
  for (int s = 0; s < CLEN; s++){
    float de = b2f(dlb[row*DI + d]);
    float u  = b2f(xcb[row*DI + d]);
    float Bv = bc[row*32 + n];
    float dA = __expf(de*a);
    h = dA*h + (de*Bv)*u;
    P *= dA;
    row += step;
  }
  size_t si = ((((size_t)dir*BB + b)*NCH + ch)*DI + d)*16 + n;
  sA[si] = P; sH[si] = h;
}

// ---------------- scan phase 2: prefix over summaries + full rescan with outputs ----------------
// y (bf16) aliases xcb: each group's u-read at row precedes lane-0 y-write at row (lockstep);
// prefetch stays within the group's own chunk.
__global__ __launch_bounds__(256) void k_scan2(
    const unsigned short* __restrict__ dlb, const unsigned short* __restrict__ xcb,
    const float* __restrict__ bc, const float* __restrict__ xz,
    const float* __restrict__ A_log, const float* __restrict__ Dp,
    const float* __restrict__ sA, const float* __restrict__ sH,
    unsigned short* __restrict__ y){
  int gid = blockIdx.x*256 + threadIdx.x;
  int n = gid & 15;
  int rest = gid >> 4;
  int d = rest % DI; rest /= DI;
  int ch = rest % NCH; rest /= NCH;
  int b = rest & 1; int dir = rest >> 1;
  float a = -__expf(A_log[d*NST + n]);
  float dD = Dp[d];
  // prefix combine: h0 for this chunk
  float h = 0.f;
  size_t sbase = (((size_t)dir*BB + b)*NCH)*DI*16 + (size_t)d*16 + n;
  for (int j = 0; j < ch; j++){
    size_t sj = sbase + (size_t)j*DI*16;
    h = sH[sj] + sA[sj]*h;
  }
  int step = dir ? -1 : 1;
  int tt = dir ? (LL-1 - ch*CLEN) : ch*CLEN;
  size_t row = (size_t)dir*ML + b*LL + tt;
  size_t zoff = (size_t)dir*ML;
  float de = b2f(dlb[row*DI + d]);
  float u  = b2f(xcb[row*DI + d]);
  float Bv = bc[row*32 + n];
  float Cv = bc[row*32 + 16 + n];
  float z  = (n == 0) ? xz[(row - zoff)*(2*DI) + DI + d] : 0.f;
  for (int s = 0; s < CLEN; s++){
    size_t nrow = row + step;
    float de2 = 0.f, u2 = 0.f, Bv2 = 0.f, Cv2 = 0.f, z2 = 0.f;
    if (s + 1 < CLEN){
      de2 = b2f(dlb[nrow*DI + d]);
      u2  = b2f(xcb[nrow*DI + d]);
      Bv2 = bc[nrow*32 + n];
      Cv2 = bc[nrow*32 + 16 + n];
      if (n == 0) z2 = xz[(nrow - zoff)*(2*DI) + DI + d];
    }
    float dA = __expf(de*a);
    h = dA*h + (de*Bv)*u;
    float p = h*Cv;
    p += __shfl_xor(p, 1, 16);
    p += __shfl_xor(p, 2, 16);
    p += __shfl_xor(p, 4, 16);
    p += __shfl_xor(p, 8, 16);
    if (n == 0) y[row*DI + d] = f2b((p + u*dD) * silu_(z));
    de = de2; u = u2; Bv = Bv2; Cv = Cv2; z = z2; row = nrow;
  }
}

// ---------------- MLP gating: g = a * silu(gate), bf16 in/out ----------------
__global__ void k_gate(const unsigned short* __restrict__ fc1o, unsigned short* __restrict__ g){
  int idx = blockIdx.x*256 + threadIdx.x;   // over 2*ML*DINT
  if (idx >= 2*ML*DINT) return;
  int i = idx % DINT; int bl = idx / DINT;
  float aa = b2f(fc1o[(size_t)bl*2*DINT + i]);
  float gt = b2f(fc1o[(size_t)bl*2*DINT + DINT + i]);
  g[idx] = f2b(aa * silu_(gt));
}

// ---------------- mean over L ----------------
__global__ void k_mean(const float* __restrict__ x, float* __restrict__ out){
  int d = blockIdx.x*256 + threadIdx.x;
  int b = blockIdx.y;
  if (d >= DM) return;
  float s = 0.f;
  for (int t = 0; t < LL; t++) s += x[((size_t)(b*LL + t))*DM + d];
  out[b*DM + d] = s*(1.f/LL);
}

extern "C" void kernel_launch(void* const* d_in, const int* in_sizes, int n_in,
                              void* d_out, int out_size, void* d_ws, size_t ws_size,
                              hipStream_t stream){
  const int*   ids     = (const int*)d_in[0];
  const float* embed   = (const float*)d_in[1];
  const float* norm_w  = (const float*)d_in[2];
  const float* norm_b  = (const float*)d_in[3];
  const float* in_proj = (const float*)d_in[4];
  const float* conv_w  = (const float*)d_in[5];
  const float* conv_b  = (const float*)d_in[6];
  const float* x_proj  = (const float*)d_in[7];
  const float* dt_w    = (const float*)d_in[8];
  const float* dt_b    = (const float*)d_in[9];
  const float* A_log   = (const float*)d_in[10];
  const float* Dp      = (const float*)d_in[11];
  const float* out_pj  = (const float*)d_in[12];
  const float* norm2_w = (const float*)d_in[13];
  const float* norm2_b = (const float*)d_in[14];
  const float* fc1     = (const float*)d_in[15];
  const float* fc2     = (const float*)d_in[16];
  const float* normf_w = (const float*)d_in[17];
  const float* normf_b = (const float*)d_in[18];
  float* out = (float*)d_out;

  const size_t BLD   = (size_t)ML*DM;
  const size_t BLDI  = (size_t)ML*DI;
  const size_t BL2DI = (size_t)ML*2*DI;
  const size_t SUMN  = (size_t)2*BB*NCH*DI*16;   // 1,572,864

  // fp32 arena
  float* f = (float*)d_ws; size_t off = 0;
  float* h     = f+off; off += BLD;
  float* res   = f+off; off += BLD;
  float* rc    = f+off; off += BLD;
  float* resd  = f+off; off += 2*BLD;
  float* xz    = f+off; off += BL2DI;      // mlpo aliases after scan
  float* bc    = f+off; off += (size_t)2*ML*32;
  float* sA    = f+off; off += SUMN;       // gb aliases (with sH) after scan2
  float* sH    = f+off; off += SUMN;
  float*          mlpo = xz;
  unsigned short* gb   = (unsigned short*)sA;
  // bf16 arena
  unsigned short* u16 = (unsigned short*)(f + off); size_t uo = 0;
  unsigned short* xlnb = u16+uo; uo += BLD;
  unsigned short* x2b  = u16+uo; uo += 2*BLD;
  unsigned short* xcb  = u16+uo; uo += 2*BLDI;   // y aliases; fc1o aliases xcb..dlb
  unsigned short* dlb  = u16+uo; uo += 2*BLDI;
  unsigned short* wib  = u16+uo; uo += (size_t)2*DI*DM;   // wf1b aliases
  unsigned short* wob  = u16+uo; uo += (size_t)DM*DI;     // wf2b aliases
  unsigned short* wbig = u16+uo; uo += (size_t)1664*DI;
  unsigned short* yb   = xcb;
  unsigned short* fc1o = xcb;     // spans xcb+dlb = 2*ML*2*DINT
  unsigned short* wf1b = wib;
  unsigned short* wf2b = wob;
  (void)ws_size; (void)in_sizes; (void)n_in; (void)out_size;

  dim3 blk(256);
  auto cdiv = [](int a, int b){ return (a + b - 1)/b; };

  k_embed<<<cdiv(ML*DM,256), blk, 0, stream>>>(ids, embed, h);

  for (int l = 0; l < NLAYER; l++){
    const float* nw  = norm_w  + l*DM;
    const float* nb  = norm_b  + l*DM;
    const float* ip  = in_proj + (size_t)l*2*DI*DM;
    const float* cw  = conv_w  + (size_t)l*DI*4;
    const float* cb  = conv_b  + (size_t)l*DI;
    const float* xp  = x_proj  + (size_t)l*(DTR+2*NST)*DI;
    const float* dw  = dt_w    + (size_t)l*DI*DTR;
    const float* db  = dt_b    + (size_t)l*DI;
    const float* al  = A_log   + (size_t)l*DI*NST;
    const float* dpl = Dp      + (size_t)l*DI;
    const float* op  = out_pj  + (size_t)l*DM*DI;
    const float* n2w = norm2_w + l*DM;
    const float* n2b = norm2_b + l*DM;
    const float* f1  = fc1 + (size_t)l*2*DINT*DM;
    const float* f2  = fc2 + (size_t)l*DM*DINT;

    // weight prep
    k_f2b<<<cdiv(2*DI*DM,256), blk, 0, stream>>>(ip, wib, 2*DI*DM);
    k_f2b<<<cdiv(DM*DI,256), blk, 0, stream>>>(op, wob, DM*DI);
    k_weff<<<cdiv(DI*DI,256), blk, 0, stream>>>(dw, xp, wbig);
    k_wtail<<<cdiv(128*DI,256), blk, 0, stream>>>(xp, wbig);

    // rc = h (+ res); xlnb = bf16(LN(rc))
    k_ln<<<ML/4, blk, 0, stream>>>(h, (l==0)?nullptr:res, nw, nb, rc, nullptr, xlnb, 0, ML);
    // xz = xln @ in_proj^T (shared across directions)
    k_mgemm<<<dim3(2*DI/128, ML/128), blk, 0, stream>>>(xlnb, wib, nullptr, xz, nullptr, 2*DI, DM, 0, nullptr, nullptr, nullptr);
    // conv both dirs -> xcb bf16
    k_conv<<<cdiv(2*ML*DI,256), blk, 0, stream>>>(xz, cw, cb, xcb);
    // fused [delta | B C | pad] GEMM, both dirs batched (M=4096)
    k_mgemm<<<dim3(1664/128, 2*ML/128), blk, 0, stream>>>(xcb, wbig, nullptr, nullptr, nullptr, 1664, DI, 1, db, dlb, bc);
    // chunked scan
    k_scan1<<<(int)(SUMN/256), blk, 0, stream>>>(dlb, xcb, bc, al, sA, sH);
    k_scan2<<<(int)(SUMN/256), blk, 0, stream>>>(dlb, xcb, bc, xz, al, dpl, sA, sH, yb);
    // fc1 weights (reuse wib region; in_proj GEMM done)
    k_f2b<<<cdiv(2*DINT*DM,256), blk, 0, stream>>>(f1, wf1b, 2*DINT*DM);
    // resd = y @ out_proj^T + rc (both dirs batched)
    k_mgemm<<<dim3(DM/128, 2*ML/128), blk, 0, stream>>>(yb, wob, rc, resd, nullptr, DM, DI, 0, nullptr, nullptr, nullptr);
    // fc2 weights (reuse wob region; out_proj GEMM done)
    k_f2b<<<cdiv(DM*DINT,256), blk, 0, stream>>>(f2, wf2b, DM*DINT);
    // LN2 both dirs -> x2b
    k_ln<<<2*ML/4, blk, 0, stream>>>(resd, nullptr, n2w, n2b, nullptr, nullptr, x2b, 0, 2*ML);
    // fc1 (M=4096) -> bf16 fc1o (aliases xcb+dlb, both free now)
    k_mgemm<<<dim3(2*DINT/128, 2*ML/128), blk, 0, stream>>>(x2b, wf1b, nullptr, nullptr, fc1o, 2*DINT, DM, 2, nullptr, nullptr, nullptr);
    // gate -> gb (aliases sA/sH)
    k_gate<<<cdiv(2*ML*DINT,256), blk, 0, stream>>>(fc1o, gb);
    // fc2 (M=4096) -> mlpo fp32 (aliases xz)
    k_mgemm<<<dim3(DM/128, 2*ML/128), blk, 0, stream>>>(gb, wf2b, nullptr, mlpo, nullptr, DM, DINT, 0, nullptr, nullptr, nullptr);
    // h = LN_f(mlpo_f) + LN_f(mlpo_b)
    k_ln<<<ML/4, blk, 0, stream>>>(mlpo, nullptr, normf_w, normf_b, nullptr, h, nullptr, 0, ML);
    k_ln<<<ML/4, blk, 0, stream>>>(mlpo + BLD, nullptr, normf_w, normf_b, nullptr, h, nullptr, 1, ML);
    // res = resd0 + resd1
    k_add<<<cdiv(ML*DM,256), blk, 0, stream>>>(resd, resd + BLD, res, ML*DM);
  }

  // final: LN(h + res) -> rc; mean over L
  k_ln<<<ML/4, blk, 0, stream>>>(h, res, normf_w, normf_b, nullptr, rc, nullptr, 0, ML);
  k_mean<<<dim3(3, BB), blk, 0, stream>>>(rc, out);
}